// Round 4
// baseline (596.957 us; speedup 1.0000x reference)
//
#include <hip/hip_runtime.h>

#define N_NODES 50000
#define N_EDGES 800000
#define IN_DIM  128
#define EDGE_DIM 64
#define OUT_DIM 128
#define NTILES  (N_EDGES / 128)   // 6250 exact

typedef __attribute__((ext_vector_type(8))) short bf16x8;
typedef __attribute__((ext_vector_type(4))) float f32x4;
typedef unsigned short u16;

__device__ __forceinline__ u16 f2bf(float f) {
    union { float f; unsigned u; } x; x.f = f;
    unsigned r = x.u + 0x7FFFu + ((x.u >> 16) & 1u);
    return (u16)(r >> 16);
}
__device__ __forceinline__ float bf2f(u16 h) {
    union { unsigned u; float f; } x; x.u = ((unsigned)h) << 16;
    return x.f;
}
__device__ __forceinline__ bf16x8 pack8(const float* v) {
    bf16x8 r;
#pragma unroll
    for (int i = 0; i < 8; ++i) r[i] = (short)f2bf(v[i]);
    return r;
}

// ---------------------------------------------------------------------------
// W2fT[o][c] = sum_i W_edge[c][i] * W_ne[IN_DIM + i][o]  (stored [128][64])
// ---------------------------------------------------------------------------
__global__ void fuse_w2_kernel(const float* __restrict__ W_edge,
                               const float* __restrict__ W_ne,
                               float* __restrict__ W2fT) {
    const int idx = blockIdx.x * blockDim.x + threadIdx.x;
    if (idx >= EDGE_DIM * OUT_DIM) return;
    const int c = idx >> 7;
    const int o = idx & 127;
    float acc = 0.0f;
    for (int i = 0; i < OUT_DIM; ++i)
        acc += W_edge[c * OUT_DIM + i] * W_ne[(IN_DIM + i) * OUT_DIM + o];
    W2fT[o * EDGE_DIM + c] = acc;
}

// ---------------------------------------------------------------------------
// Dual node GEMM: H1 = nfeat @ W_ne[:128] (bf16), HS = nfeat @ W_self + b_self
// 256 threads: cols 0-127 -> H1, 128-255 -> HS. nfeat read once.
// ---------------------------------------------------------------------------
__global__ __launch_bounds__(256, 2) void node_gemm_dual_kernel(
    const float* __restrict__ nfeat, const float* __restrict__ W_ne,
    const float* __restrict__ W_self, const float* __restrict__ b_self,
    u16* __restrict__ H1, u16* __restrict__ HS) {
    __shared__ float4 hh[4][32];
    const int t = threadIdx.x;
    const int o = t & 127;
    const bool self = (t >= 128);
    const float* W = self ? W_self : W_ne;   // W_ne rows [0,128) == W1
    float w[128];
#pragma unroll
    for (int k = 0; k < 128; ++k) w[k] = W[k * OUT_DIM + o];
    const float b = self ? b_self[o] : 0.0f;
    u16* Y = self ? HS : H1;

    const int npass = N_NODES / 4;
    for (int p = blockIdx.x; p < npass; p += gridDim.x) {
        const int r0 = p * 4;
        if (t < 128) hh[t >> 5][t & 31] = ((const float4*)(nfeat + (size_t)r0 * 128))[t];
        __syncthreads();
        float a0 = b, a1 = b, a2 = b, a3 = b;
#pragma unroll
        for (int k4 = 0; k4 < 32; ++k4) {
            float4 h0 = hh[0][k4], h1 = hh[1][k4], h2 = hh[2][k4], h3 = hh[3][k4];
            a0 = fmaf(h0.x, w[4*k4+0], a0); a0 = fmaf(h0.y, w[4*k4+1], a0);
            a0 = fmaf(h0.z, w[4*k4+2], a0); a0 = fmaf(h0.w, w[4*k4+3], a0);
            a1 = fmaf(h1.x, w[4*k4+0], a1); a1 = fmaf(h1.y, w[4*k4+1], a1);
            a1 = fmaf(h1.z, w[4*k4+2], a1); a1 = fmaf(h1.w, w[4*k4+3], a1);
            a2 = fmaf(h2.x, w[4*k4+0], a2); a2 = fmaf(h2.y, w[4*k4+1], a2);
            a2 = fmaf(h2.z, w[4*k4+2], a2); a2 = fmaf(h2.w, w[4*k4+3], a2);
            a3 = fmaf(h3.x, w[4*k4+0], a3); a3 = fmaf(h3.y, w[4*k4+1], a3);
            a3 = fmaf(h3.z, w[4*k4+2], a3); a3 = fmaf(h3.w, w[4*k4+3], a3);
        }
        Y[(size_t)(r0 + 0) * 128 + o] = f2bf(a0);
        Y[(size_t)(r0 + 1) * 128 + o] = f2bf(a1);
        Y[(size_t)(r0 + 2) * 128 + o] = f2bf(a2);
        Y[(size_t)(r0 + 3) * 128 + o] = f2bf(a3);
        __syncthreads();
    }
}

// ---------------------------------------------------------------------------
// CSR build
// ---------------------------------------------------------------------------
__global__ void count_rank_kernel(const int* __restrict__ dst,
                                  int* __restrict__ counts, int* __restrict__ rank) {
    const int e = blockIdx.x * blockDim.x + threadIdx.x;
    if (e < N_EDGES) rank[e] = atomicAdd(&counts[dst[e]], 1);
}

#define SCAN_T 1024
#define SCAN_CHUNK 49
__global__ void scan_kernel(const int* __restrict__ counts, int* __restrict__ off) {
    __shared__ int part[SCAN_T];
    const int t = threadIdx.x;
    const int base = t * SCAN_CHUNK;
    int s = 0;
    for (int k = 0; k < SCAN_CHUNK; ++k) {
        const int i = base + k;
        if (i < N_NODES) s += counts[i];
    }
    part[t] = s;
    __syncthreads();
    for (int d = 1; d < SCAN_T; d <<= 1) {
        int v = (t >= d) ? part[t - d] : 0;
        __syncthreads();
        part[t] += v;
        __syncthreads();
    }
    int excl = part[t] - s;
    for (int k = 0; k < SCAN_CHUNK; ++k) {
        const int i = base + k;
        if (i < N_NODES) { off[i] = excl; excl += counts[i]; }
    }
    if (t == SCAN_T - 1) off[N_NODES] = excl;
}

__global__ void scatter_kernel(const int* __restrict__ dst, const int* __restrict__ src,
                               const int* __restrict__ rank, const int* __restrict__ off,
                               int* __restrict__ eid, int* __restrict__ srcS,
                               int* __restrict__ dstS) {
    const int e = blockIdx.x * blockDim.x + threadIdx.x;
    if (e < N_EDGES) {
        const int d = dst[e];
        const int slot = off[d] + rank[e];
        eid[slot]  = e;
        srcS[slot] = src[e];
        dstS[slot] = d;
    }
}

// ---------------------------------------------------------------------------
// zero the output accumulator
// ---------------------------------------------------------------------------
__global__ void zero_out_kernel(float* __restrict__ out) {
    const int stride = gridDim.x * blockDim.x;
    float4 z = {0.f, 0.f, 0.f, 0.f};
    for (int j = blockIdx.x * blockDim.x + threadIdx.x; j < (N_NODES * OUT_DIM) / 4; j += stride)
        ((float4*)out)[j] = z;
}

// ---------------------------------------------------------------------------
// FUSED edge kernel over dst-sorted slots. Per 128-slot tile:
//   gather efeat[eid] -> bf16 swizzled LDS -> MFMA (E2 = efeat@W2f + b)
//   v = relu(E2 + H1[srcS])  -> swizzled LDS m-tile
//   segmented column reduce by dstS: interior runs -> plain store,
//   boundary runs -> fp32 atomicAdd.  (out holds raw segment sums.)
// ---------------------------------------------------------------------------
__global__ __launch_bounds__(256, 2) void fused_edge_kernel(
    const float* __restrict__ efeat, const int* __restrict__ eid,
    const int* __restrict__ srcS, const int* __restrict__ dstS,
    const float* __restrict__ W2fT, const float* __restrict__ b_ne,
    const u16* __restrict__ H1, float* __restrict__ out) {

    __shared__ __align__(16) char Ab[128 * 64 * 2];    // 16 KB A-tile (bf16, swizzled)
    __shared__ __align__(16) char Mb[128 * 128 * 2];   // 32 KB m-tile (bf16, swizzled)
    __shared__ int eL[128], sL[128], dL[128];

    const int tid  = threadIdx.x;
    const int w    = tid >> 6;
    const int l    = tid & 63;
    const int lrow = l & 15;
    const int lq   = l >> 4;
    const int h    = tid >> 7;      // half for reduce phase
    const int o    = tid & 127;     // column for reduce phase

    // B fragments (W2fT) + bias, loaded once per block
    bf16x8 Bf[8][2];
    float bias[8];
#pragma unroll
    for (int nt = 0; nt < 8; ++nt) {
        bias[nt] = b_ne[nt * 16 + lrow];
#pragma unroll
        for (int kk = 0; kk < 2; ++kk) {
            const float* wp = W2fT + (nt * 16 + lrow) * 64 + kk * 32 + lq * 8;
            float tmp[8];
#pragma unroll
            for (int j = 0; j < 8; ++j) tmp[j] = wp[j];
            Bf[nt][kk] = pack8(tmp);
        }
    }

    const int srow = tid >> 1;
    const int skh  = (tid & 1) * 32;

    for (int tile = blockIdx.x; tile < NTILES; tile += gridDim.x) {
        const int t0 = tile * 128;

        if (tid < 128) {
            eL[tid] = eid[t0 + tid];
            sL[tid] = srcS[t0 + tid];
            dL[tid] = dstS[t0 + tid];
        }
        __syncthreads();   // B1: eL ready; prev tile's Mb/dL consumers done

        // ---- stage gathered efeat rows -> bf16 swizzled LDS
        const float4* ep = (const float4*)(efeat + (size_t)eL[srow] * 64 + skh);
#pragma unroll
        for (int j = 0; j < 4; ++j) {
            float4 x = ep[2 * j], y = ep[2 * j + 1];
            float tmp[8] = {x.x, x.y, x.z, x.w, y.x, y.y, y.z, y.w};
            bf16x8 f = pack8(tmp);
            int addr = (srow * 128 + skh * 2 + j * 16) ^ ((srow & 7) << 4);
            *(bf16x8*)(Ab + addr) = f;
        }
        __syncthreads();   // B2: Ab ready

        // ---- MFMA
        f32x4 acc[2][8];
#pragma unroll
        for (int mt = 0; mt < 2; ++mt)
#pragma unroll
            for (int nt = 0; nt < 8; ++nt) {
                acc[mt][nt][0] = bias[nt]; acc[mt][nt][1] = bias[nt];
                acc[mt][nt][2] = bias[nt]; acc[mt][nt][3] = bias[nt];
            }
        bf16x8 Af[2][2];
#pragma unroll
        for (int mt = 0; mt < 2; ++mt)
#pragma unroll
            for (int kk = 0; kk < 2; ++kk) {
                int row  = w * 32 + mt * 16 + lrow;
                int addr = (row * 128 + kk * 64 + lq * 16) ^ ((row & 7) << 4);
                Af[mt][kk] = *(const bf16x8*)(Ab + addr);
            }
#pragma unroll
        for (int mt = 0; mt < 2; ++mt)
#pragma unroll
            for (int nt = 0; nt < 8; ++nt) {
                acc[mt][nt] = __builtin_amdgcn_mfma_f32_16x16x32_bf16(Af[mt][0], Bf[nt][0], acc[mt][nt], 0, 0, 0);
                acc[mt][nt] = __builtin_amdgcn_mfma_f32_16x16x32_bf16(Af[mt][1], Bf[nt][1], acc[mt][nt], 0, 0, 0);
            }

        // ---- epilogue: v = relu(E2 + H1[src]) -> Mb (swizzled)
#pragma unroll
        for (int mt = 0; mt < 2; ++mt) {
#pragma unroll
            for (int j = 0; j < 4; ++j) {
                const int row = w * 32 + mt * 16 + lq * 4 + j;
                const u16* hp = H1 + (size_t)sL[row] * 128;
#pragma unroll
                for (int nt = 0; nt < 8; ++nt) {
                    const int col = nt * 16 + lrow;
                    float v = fmaxf(acc[mt][nt][j] + bf2f(hp[col]), 0.0f);
                    int addr = row * 256 + ((col * 2) ^ ((row & 7) << 4));
                    *(u16*)(Mb + addr) = f2bf(v);
                }
            }
        }
        __syncthreads();   // B3: Mb ready

        // ---- segmented column reduce (wave-uniform branches: dL scan is
        //      identical across the 64 lanes of a wave; lanes differ in o)
        {
            const int r0 = h * 64, r1 = r0 + 64;
            int dprev = dL[r0];
            int rs = r0;
            float acc2 = bf2f(*(const u16*)(Mb + r0 * 256 + ((o * 2) ^ ((r0 & 7) << 4))));
            for (int r = r0 + 1; r < r1; ++r) {
                const int d = dL[r];
                const float v = bf2f(*(const u16*)(Mb + r * 256 + ((o * 2) ^ ((r & 7) << 4))));
                if (d != dprev) {
                    // flush [rs, r): right-bounded in-half; interior iff left-bounded too
                    if (rs > r0) out[(size_t)dprev * 128 + o] = acc2;          // complete node
                    else         atomicAdd(out + (size_t)dprev * 128 + o, acc2);
                    rs = r; dprev = d; acc2 = v;
                } else {
                    acc2 += v;
                }
            }
            // final flush [rs, r1): peek across half boundary when possible
            if (h == 0 && rs > r0 && dL[64] != dprev)
                out[(size_t)dprev * 128 + o] = acc2;
            else
                atomicAdd(out + (size_t)dprev * 128 + o, acc2);
        }
        __syncthreads();   // B4: Mb/eL/sL/dL free for next tile
    }
}

// ---------------------------------------------------------------------------
// finalize: out[n] = out[n] / max(cnt[n],1) + HS[n]
// ---------------------------------------------------------------------------
__global__ void finalize_kernel(float* __restrict__ out, const int* __restrict__ counts,
                                const u16* __restrict__ HS) {
    const int stride = gridDim.x * blockDim.x;
    for (int i = blockIdx.x * blockDim.x + threadIdx.x; i < N_NODES * 32; i += stride) {
        const int row = i >> 5;
        const int c = counts[row];
        const float inv = (c > 0) ? 1.0f / (float)c : 0.0f;
        float4 v = ((const float4*)out)[i];
        ushort4 hs = ((const ushort4*)HS)[i];
        float4 r;
        r.x = v.x * inv + bf2f(hs.x);
        r.y = v.y * inv + bf2f(hs.y);
        r.z = v.z * inv + bf2f(hs.z);
        r.w = v.w * inv + bf2f(hs.w);
        ((float4*)out)[i] = r;
    }
}

// ---------------------------------------------------------------------------
extern "C" void kernel_launch(void* const* d_in, const int* in_sizes, int n_in,
                              void* d_out, int out_size, void* d_ws, size_t ws_size,
                              hipStream_t stream) {
    const float* nfeat  = (const float*)d_in[0];
    const float* efeat  = (const float*)d_in[1];
    const int*   src    = (const int*)d_in[2];
    const int*   dst    = (const int*)d_in[3];
    const float* W_edge = (const float*)d_in[4];
    const float* W_ne   = (const float*)d_in[5];
    const float* b_ne   = (const float*)d_in[6];
    const float* W_self = (const float*)d_in[7];
    const float* b_self = (const float*)d_in[8];

    float* out = (float*)d_out;
    char* ws = (char*)d_ws;

    // ws layout (~36.7 MB; harness provided >=237 MB in round 3)
    const size_t OFF_W2   = 0;                        // 32768 B
    const size_t OFF_CNT  = 32768;                    // 200000 B
    const size_t OFF_OFFS = OFF_CNT + 200000;         // 200064 B
    const size_t OFF_RANK = OFF_OFFS + 200064;        // 3.2 MB
    const size_t OFF_EID  = OFF_RANK + 3200000;       // 3.2 MB
    const size_t OFF_SRCS = OFF_EID + 3200000;        // 3.2 MB
    const size_t OFF_DSTS = OFF_SRCS + 3200000;       // 3.2 MB
    const size_t OFF_H1   = OFF_DSTS + 3200000;       // 12.8 MB
    const size_t OFF_HS   = OFF_H1 + 12800000;        // 12.8 MB

    float* W2fT = (float*)(ws + OFF_W2);
    int*   cnts = (int*)(ws + OFF_CNT);
    int*   offs = (int*)(ws + OFF_OFFS);
    int*   rank = (int*)(ws + OFF_RANK);
    int*   eid  = (int*)(ws + OFF_EID);
    int*   srcS = (int*)(ws + OFF_SRCS);
    int*   dstS = (int*)(ws + OFF_DSTS);
    u16*   H1   = (u16*)(ws + OFF_H1);
    u16*   HS   = (u16*)(ws + OFF_HS);

    hipMemsetAsync(cnts, 0, N_NODES * sizeof(int), stream);
    fuse_w2_kernel<<<32, 256, 0, stream>>>(W_edge, W_ne, W2fT);
    node_gemm_dual_kernel<<<2048, 256, 0, stream>>>(nfeat, W_ne, W_self, b_self, H1, HS);
    count_rank_kernel<<<(N_EDGES + 255) / 256, 256, 0, stream>>>(dst, cnts, rank);
    scan_kernel<<<1, SCAN_T, 0, stream>>>(cnts, offs);
    scatter_kernel<<<(N_EDGES + 255) / 256, 256, 0, stream>>>(dst, src, rank, offs, eid, srcS, dstS);
    zero_out_kernel<<<2048, 256, 0, stream>>>(out);
    fused_edge_kernel<<<2048, 256, 0, stream>>>(efeat, eid, srcS, dstS, W2fT, b_ne, H1, out);
    finalize_kernel<<<2048, 256, 0, stream>>>(out, cnts, HS);
}

// Round 5
// 426.086 us; speedup vs baseline: 1.4010x; 1.4010x over previous
//
#include <hip/hip_runtime.h>

#define N_NODES 50000
#define N_EDGES 800000
#define IN_DIM  128
#define EDGE_DIM 64
#define OUT_DIM 128
#define NTILES  (N_EDGES / 128)   // 6250 exact

typedef __attribute__((ext_vector_type(8))) short bf16x8;
typedef __attribute__((ext_vector_type(4))) float f32x4;
typedef unsigned short u16;

__device__ __forceinline__ u16 f2bf(float f) {
    union { float f; unsigned u; } x; x.f = f;
    unsigned r = x.u + 0x7FFFu + ((x.u >> 16) & 1u);
    return (u16)(r >> 16);
}
__device__ __forceinline__ float bf2f(u16 h) {
    union { unsigned u; float f; } x; x.u = ((unsigned)h) << 16;
    return x.f;
}
__device__ __forceinline__ bf16x8 pack8(const float* v) {
    bf16x8 r;
#pragma unroll
    for (int i = 0; i < 8; ++i) r[i] = (short)f2bf(v[i]);
    return r;
}

// ---------------------------------------------------------------------------
// W2fT[o][c] = sum_i W_edge[c][i] * W_ne[IN_DIM + i][o]  (stored [128][64])
// ---------------------------------------------------------------------------
__global__ void fuse_w2_kernel(const float* __restrict__ W_edge,
                               const float* __restrict__ W_ne,
                               float* __restrict__ W2fT) {
    const int idx = blockIdx.x * blockDim.x + threadIdx.x;
    if (idx >= EDGE_DIM * OUT_DIM) return;
    const int c = idx >> 7;
    const int o = idx & 127;
    float acc = 0.0f;
    for (int i = 0; i < OUT_DIM; ++i)
        acc += W_edge[c * OUT_DIM + i] * W_ne[(IN_DIM + i) * OUT_DIM + o];
    W2fT[o * EDGE_DIM + c] = acc;
}

// ---------------------------------------------------------------------------
// Dual node GEMM: H1 = nfeat @ W_ne[:128] (bf16), HS = nfeat @ W_self + b_self
// ---------------------------------------------------------------------------
__global__ __launch_bounds__(256, 2) void node_gemm_dual_kernel(
    const float* __restrict__ nfeat, const float* __restrict__ W_ne,
    const float* __restrict__ W_self, const float* __restrict__ b_self,
    u16* __restrict__ H1, u16* __restrict__ HS) {
    __shared__ float4 hh[4][32];
    const int t = threadIdx.x;
    const int o = t & 127;
    const bool self = (t >= 128);
    const float* W = self ? W_self : W_ne;   // W_ne rows [0,128) == W1
    float w[128];
#pragma unroll
    for (int k = 0; k < 128; ++k) w[k] = W[k * OUT_DIM + o];
    const float b = self ? b_self[o] : 0.0f;
    u16* Y = self ? HS : H1;

    const int npass = N_NODES / 4;
    for (int p = blockIdx.x; p < npass; p += gridDim.x) {
        const int r0 = p * 4;
        if (t < 128) hh[t >> 5][t & 31] = ((const float4*)(nfeat + (size_t)r0 * 128))[t];
        __syncthreads();
        float a0 = b, a1 = b, a2 = b, a3 = b;
#pragma unroll
        for (int k4 = 0; k4 < 32; ++k4) {
            float4 h0 = hh[0][k4], h1 = hh[1][k4], h2 = hh[2][k4], h3 = hh[3][k4];
            a0 = fmaf(h0.x, w[4*k4+0], a0); a0 = fmaf(h0.y, w[4*k4+1], a0);
            a0 = fmaf(h0.z, w[4*k4+2], a0); a0 = fmaf(h0.w, w[4*k4+3], a0);
            a1 = fmaf(h1.x, w[4*k4+0], a1); a1 = fmaf(h1.y, w[4*k4+1], a1);
            a1 = fmaf(h1.z, w[4*k4+2], a1); a1 = fmaf(h1.w, w[4*k4+3], a1);
            a2 = fmaf(h2.x, w[4*k4+0], a2); a2 = fmaf(h2.y, w[4*k4+1], a2);
            a2 = fmaf(h2.z, w[4*k4+2], a2); a2 = fmaf(h2.w, w[4*k4+3], a2);
            a3 = fmaf(h3.x, w[4*k4+0], a3); a3 = fmaf(h3.y, w[4*k4+1], a3);
            a3 = fmaf(h3.z, w[4*k4+2], a3); a3 = fmaf(h3.w, w[4*k4+3], a3);
        }
        Y[(size_t)(r0 + 0) * 128 + o] = f2bf(a0);
        Y[(size_t)(r0 + 1) * 128 + o] = f2bf(a1);
        Y[(size_t)(r0 + 2) * 128 + o] = f2bf(a2);
        Y[(size_t)(r0 + 3) * 128 + o] = f2bf(a3);
        __syncthreads();
    }
}

// ---------------------------------------------------------------------------
// CSR build: count/rank -> scan -> slotOf (inverse permutation)
// ---------------------------------------------------------------------------
__global__ void count_rank_kernel(const int* __restrict__ dst,
                                  int* __restrict__ counts, int* __restrict__ rank) {
    const int e = blockIdx.x * blockDim.x + threadIdx.x;
    if (e < N_EDGES) rank[e] = atomicAdd(&counts[dst[e]], 1);
}

#define SCAN_T 1024
#define SCAN_CHUNK 49
__global__ void scan_kernel(const int* __restrict__ counts, int* __restrict__ off) {
    __shared__ int part[SCAN_T];
    const int t = threadIdx.x;
    const int base = t * SCAN_CHUNK;
    int s = 0;
    for (int k = 0; k < SCAN_CHUNK; ++k) {
        const int i = base + k;
        if (i < N_NODES) s += counts[i];
    }
    part[t] = s;
    __syncthreads();
    for (int d = 1; d < SCAN_T; d <<= 1) {
        int v = (t >= d) ? part[t - d] : 0;
        __syncthreads();
        part[t] += v;
        __syncthreads();
    }
    int excl = part[t] - s;
    for (int k = 0; k < SCAN_CHUNK; ++k) {
        const int i = base + k;
        if (i < N_NODES) { off[i] = excl; excl += counts[i]; }
    }
    if (t == SCAN_T - 1) off[N_NODES] = excl;
}

__global__ void slotof_kernel(const int* __restrict__ dst, const int* __restrict__ rank,
                              const int* __restrict__ off, int* __restrict__ slotOf) {
    const int e = blockIdx.x * blockDim.x + threadIdx.x;
    if (e < N_EDGES) slotOf[e] = off[dst[e]] + rank[e];
}

// ---------------------------------------------------------------------------
// Edge GEMM with scatter-write (round-3 structure, sequential efeat read):
//   m[e] = relu(efeat[e] @ W2f + H1[src[e]] + b_ne)  -> mbuf[slotOf[e]] (bf16)
// Random access only on the STORE side (latency-tolerant).
// ---------------------------------------------------------------------------
__global__ __launch_bounds__(256, 2) void edge_gemm_scatter_kernel(
    const float* __restrict__ efeat, const int* __restrict__ src,
    const int* __restrict__ slotOf, const float* __restrict__ W2fT,
    const float* __restrict__ b_ne, const u16* __restrict__ H1,
    u16* __restrict__ mbuf) {

    __shared__ __align__(16) char Ab[128 * 64 * 2];
    __shared__ int sS[128];   // src per row
    __shared__ int sT[128];   // slot per row

    const int tid  = threadIdx.x;
    const int w    = tid >> 6;
    const int l    = tid & 63;
    const int lrow = l & 15;
    const int lq   = l >> 4;

    bf16x8 Bf[8][2];
    float bias[8];
#pragma unroll
    for (int nt = 0; nt < 8; ++nt) {
        bias[nt] = b_ne[nt * 16 + lrow];
#pragma unroll
        for (int kk = 0; kk < 2; ++kk) {
            const float* wp = W2fT + (nt * 16 + lrow) * 64 + kk * 32 + lq * 8;
            float tmp[8];
#pragma unroll
            for (int j = 0; j < 8; ++j) tmp[j] = wp[j];
            Bf[nt][kk] = pack8(tmp);
        }
    }

    const int srow = tid >> 1;
    const int skh  = (tid & 1) * 32;

    for (int tile = blockIdx.x; tile < NTILES; tile += gridDim.x) {
        const int e0 = tile * 128;

        if (tid < 128) {
            sS[tid] = src[e0 + tid];
            sT[tid] = slotOf[e0 + tid];
        }
        // ---- stage efeat rows (sequential) -> bf16 swizzled LDS
        const float4* ep = (const float4*)(efeat + (size_t)(e0 + srow) * 64 + skh);
#pragma unroll
        for (int j = 0; j < 4; ++j) {
            float4 x = ep[2 * j], y = ep[2 * j + 1];
            float tmp[8] = {x.x, x.y, x.z, x.w, y.x, y.y, y.z, y.w};
            bf16x8 f = pack8(tmp);
            int addr = (srow * 128 + skh * 2 + j * 16) ^ ((srow & 7) << 4);
            *(bf16x8*)(Ab + addr) = f;
        }
        __syncthreads();   // Ab, sS, sT ready

        f32x4 acc[2][8];
#pragma unroll
        for (int mt = 0; mt < 2; ++mt)
#pragma unroll
            for (int nt = 0; nt < 8; ++nt) {
                acc[mt][nt][0] = bias[nt]; acc[mt][nt][1] = bias[nt];
                acc[mt][nt][2] = bias[nt]; acc[mt][nt][3] = bias[nt];
            }
        bf16x8 Af[2][2];
#pragma unroll
        for (int mt = 0; mt < 2; ++mt)
#pragma unroll
            for (int kk = 0; kk < 2; ++kk) {
                int row  = w * 32 + mt * 16 + lrow;
                int addr = (row * 128 + kk * 64 + lq * 16) ^ ((row & 7) << 4);
                Af[mt][kk] = *(const bf16x8*)(Ab + addr);
            }
#pragma unroll
        for (int mt = 0; mt < 2; ++mt)
#pragma unroll
            for (int nt = 0; nt < 8; ++nt) {
                acc[mt][nt] = __builtin_amdgcn_mfma_f32_16x16x32_bf16(Af[mt][0], Bf[nt][0], acc[mt][nt], 0, 0, 0);
                acc[mt][nt] = __builtin_amdgcn_mfma_f32_16x16x32_bf16(Af[mt][1], Bf[nt][1], acc[mt][nt], 0, 0, 0);
            }

        // ---- epilogue: gather H1[src], relu, scatter bf16 row to mbuf[slot]
#pragma unroll
        for (int mt = 0; mt < 2; ++mt) {
#pragma unroll
            for (int j = 0; j < 4; ++j) {
                const int row = w * 32 + mt * 16 + lq * 4 + j;
                const u16* hp = H1 + (size_t)sS[row] * 128;
                u16* mp = mbuf + (size_t)sT[row] * 128;
#pragma unroll
                for (int nt = 0; nt < 8; ++nt) {
                    const int col = nt * 16 + lrow;
                    float v = fmaxf(acc[mt][nt][j] + bf2f(hp[col]), 0.0f);
                    mp[col] = f2bf(v);
                }
            }
        }
        __syncthreads();   // Ab/sS/sT free for next tile
    }
}

// ---------------------------------------------------------------------------
// Streaming segment reduce + finalize:
//   out[n] = (sum over slots [off[n],off[n+1]) of mbuf rows)/max(deg,1) + HS[n]
// Segments are contiguous & in node order -> sequential mbuf read, no atomics.
// ---------------------------------------------------------------------------
__global__ __launch_bounds__(256, 4) void reduce_kernel(
    const int* __restrict__ off, const u16* __restrict__ mbuf,
    const u16* __restrict__ HS, float* __restrict__ out) {
    const int n = blockIdx.x * 2 + (threadIdx.x >> 7);
    const int o = threadIdx.x & 127;
    if (n >= N_NODES) return;
    const int s0 = off[n], s1 = off[n + 1];
    float acc = 0.0f;
    int s = s0;
    for (; s + 4 <= s1; s += 4) {
        float v0 = bf2f(mbuf[(size_t)(s + 0) * 128 + o]);
        float v1 = bf2f(mbuf[(size_t)(s + 1) * 128 + o]);
        float v2 = bf2f(mbuf[(size_t)(s + 2) * 128 + o]);
        float v3 = bf2f(mbuf[(size_t)(s + 3) * 128 + o]);
        acc += (v0 + v1) + (v2 + v3);
    }
    for (; s < s1; ++s) acc += bf2f(mbuf[(size_t)s * 128 + o]);
    const int c = s1 - s0;
    const float inv = (c > 0) ? 1.0f / (float)c : 0.0f;
    out[(size_t)n * 128 + o] = acc * inv + bf2f(HS[(size_t)n * 128 + o]);
}

// ---------------------------------------------------------------------------
extern "C" void kernel_launch(void* const* d_in, const int* in_sizes, int n_in,
                              void* d_out, int out_size, void* d_ws, size_t ws_size,
                              hipStream_t stream) {
    const float* nfeat  = (const float*)d_in[0];
    const float* efeat  = (const float*)d_in[1];
    const int*   src    = (const int*)d_in[2];
    const int*   dst    = (const int*)d_in[3];
    const float* W_edge = (const float*)d_in[4];
    const float* W_ne   = (const float*)d_in[5];
    const float* b_ne   = (const float*)d_in[6];
    const float* W_self = (const float*)d_in[7];
    const float* b_self = (const float*)d_in[8];

    float* out = (float*)d_out;
    char* ws = (char*)d_ws;

    // ws layout (~237.2 MB; proven available in rounds 3/4)
    const size_t OFF_W2   = 0;                        // 32768 B
    const size_t OFF_CNT  = 32768;                    // 200000 B
    const size_t OFF_OFFS = OFF_CNT + 200000;         // 200064 B
    const size_t OFF_RANK = OFF_OFFS + 200064;        // 3.2 MB
    const size_t OFF_SLOT = OFF_RANK + 3200000;       // 3.2 MB
    const size_t OFF_H1   = OFF_SLOT + 3200000;       // 12.8 MB
    const size_t OFF_HS   = OFF_H1 + 12800000;        // 12.8 MB
    const size_t OFF_M    = OFF_HS + 12800000;        // 204.8 MB

    float* W2fT   = (float*)(ws + OFF_W2);
    int*   cnts   = (int*)(ws + OFF_CNT);
    int*   offs   = (int*)(ws + OFF_OFFS);
    int*   rank   = (int*)(ws + OFF_RANK);
    int*   slotOf = (int*)(ws + OFF_SLOT);
    u16*   H1     = (u16*)(ws + OFF_H1);
    u16*   HS     = (u16*)(ws + OFF_HS);
    u16*   mbuf   = (u16*)(ws + OFF_M);

    hipMemsetAsync(cnts, 0, N_NODES * sizeof(int), stream);
    fuse_w2_kernel<<<32, 256, 0, stream>>>(W_edge, W_ne, W2fT);
    node_gemm_dual_kernel<<<2048, 256, 0, stream>>>(nfeat, W_ne, W_self, b_self, H1, HS);
    count_rank_kernel<<<(N_EDGES + 255) / 256, 256, 0, stream>>>(dst, cnts, rank);
    scan_kernel<<<1, SCAN_T, 0, stream>>>(cnts, offs);
    slotof_kernel<<<(N_EDGES + 255) / 256, 256, 0, stream>>>(dst, rank, offs, slotOf);
    edge_gemm_scatter_kernel<<<2048, 256, 0, stream>>>(efeat, src, slotOf, W2fT, b_ne, H1, mbuf);
    reduce_kernel<<<(N_NODES + 1) / 2, 256, 0, stream>>>(offs, mbuf, HS, out);
}